// Round 5
// baseline (316.858 us; speedup 1.0000x reference)
//
#include <hip/hip_runtime.h>
#include <hip/hip_bf16.h>

typedef __bf16 bf16x8 __attribute__((ext_vector_type(8)));
typedef __bf16 bf16x4 __attribute__((ext_vector_type(4)));
typedef __bf16 bf16x2 __attribute__((ext_vector_type(2)));
typedef float  f32x4  __attribute__((ext_vector_type(4)));
typedef float  f32x16 __attribute__((ext_vector_type(16)));
typedef unsigned uint4v __attribute__((ext_vector_type(4)));

#define MFMA_BF16(a, b, c) __builtin_amdgcn_mfma_f32_16x16x32_bf16((a), (b), (c), 0, 0, 0)
#define MFMA32(a, b, c) __builtin_amdgcn_mfma_f32_32x32x16_bf16((a), (b), (c), 0, 0, 0)

typedef const __attribute__((address_space(1))) void* gas_ptr;
typedef __attribute__((address_space(3))) void* las_ptr;

__device__ __forceinline__ void gload_lds16(const void* g, void* l) {
    // async global->LDS, 16B per lane; LDS dest = uniform base + lane*16
    __builtin_amdgcn_global_load_lds((gas_ptr)g, (las_ptr)l, 16, 0, 0);
}

#define LOG2E 1.44269504088896f
#define QSCALE 0.1803368801111204f  // 0.125 * log2(e): folded into Q at GEMM1 epilogue

// ---------------------------------------------------------------------------
// elementwise f32 -> bf16 (float4 in, bf16x4 out)
__global__ __launch_bounds__(256) void cvt_f32_bf16(const float* __restrict__ in,
                                                    __bf16* __restrict__ out, int n4) {
    int i = blockIdx.x * 256 + threadIdx.x;
    if (i < n4) {
        float4 v = ((const float4*)in)[i];
        bf16x4 o = {(__bf16)v.x, (__bf16)v.y, (__bf16)v.z, (__bf16)v.w};
        ((bf16x4*)out)[i] = o;
    }
}

// transpose [R,C] f32 -> [C,R] bf16 (R,C multiples of 32); block (32,8)
__global__ __launch_bounds__(256) void transpose_cvt(const float* __restrict__ in,
                                                     __bf16* __restrict__ out, int R, int C) {
    __shared__ float t[32][33];
    int bx = blockIdx.x * 32, by = blockIdx.y * 32;
    int x = bx + threadIdx.x;
    for (int j = threadIdx.y; j < 32; j += 8)
        t[j][threadIdx.x] = in[(size_t)(by + j) * C + x];
    __syncthreads();
    int x2 = by + threadIdx.x;
    for (int j = threadIdx.y; j < 32; j += 8)
        out[(size_t)(bx + j) * R + x2] = (__bf16)t[threadIdx.x][j];
}

// ---------------------------------------------------------------------------
// GEMM: C[M,Nn] = A[M,K] * Bt[Nn,K]^T + bias.  128x128 tile, BK=32.
// MODE 0: scatter bf16 into Q (prescaled by QSCALE) [B,H,N,D], K [B,H,N,D],
//         and V TRANSPOSED [B,H,D,N] (c = s*1024 + h*64 + d)
// MODE 1: fp32 out[M,Nn]
template <int MODE>
__global__ __launch_bounds__(256) void gemm_bt(const __bf16* __restrict__ A,
                                               const __bf16* __restrict__ Bt,
                                               const float* __restrict__ bias,
                                               float* __restrict__ outp,
                                               __bf16* __restrict__ Qp,
                                               __bf16* __restrict__ Kp,
                                               __bf16* __restrict__ Vp,
                                               int M, int Nn, int K) {
    __shared__ __align__(16) __bf16 As[128 * 32];
    __shared__ __align__(16) __bf16 Bs[128 * 32];
    const int tid = threadIdx.x, lane = tid & 63, w = tid >> 6;
    const int wr = w >> 1, wc = w & 1;
    const int row0 = blockIdx.y * 128, col0 = blockIdx.x * 128;
    const __bf16* Ag = A + (size_t)row0 * K;
    const __bf16* Bg = Bt + (size_t)col0 * K;
    const int lr = lane >> 2;        // 0..15 row within 16-row chunk
    const int lk = (lane & 3) * 8;   // 0/8/16/24 col offset
    const int frow = lane & 15, fq = lane >> 4;
    f32x4 acc[4][4];
    for (int i = 0; i < 4; ++i)
        for (int j = 0; j < 4; ++j) acc[i][j] = (f32x4)0.f;

    for (int k0 = 0; k0 < K; k0 += 32) {
        __syncthreads();
        for (int it = 0; it < 2; ++it) {
            int ci = 2 * w + it;  // 8 chunks of 16 rows
            gload_lds16(Ag + (size_t)(ci * 16 + lr) * K + k0 + lk, &As[ci * 512]);
            gload_lds16(Bg + (size_t)(ci * 16 + lr) * K + k0 + lk, &Bs[ci * 512]);
        }
        __syncthreads();
        bf16x8 af[4], bf[4];
        for (int i = 0; i < 4; ++i)
            af[i] = *(const bf16x8*)&As[(wr * 64 + i * 16 + frow) * 32 + fq * 8];
        for (int j = 0; j < 4; ++j)
            bf[j] = *(const bf16x8*)&Bs[(wc * 64 + j * 16 + frow) * 32 + fq * 8];
        for (int i = 0; i < 4; ++i)
            for (int j = 0; j < 4; ++j) acc[i][j] = MFMA_BF16(af[i], bf[j], acc[i][j]);
    }

    // epilogue: C/D layout col = lane&15, row = (lane>>4)*4 + reg
    for (int i = 0; i < 4; ++i) {
        int rbase = row0 + wr * 64 + i * 16 + fq * 4;
        for (int j = 0; j < 4; ++j) {
            int c = col0 + wc * 64 + j * 16 + frow;
            float bv = bias[c];
            if (MODE == 0) {
                int which = c >> 10;
                int h = (c >> 6) & 15;
                int d = c & 63;
                if (which == 2) {
                    // V^T: consecutive rg = consecutive n -> contiguous bf16x4
                    int b = rbase >> 11, n = rbase & 2047;
                    bf16x4 vv = {(__bf16)(acc[i][j][0] + bv), (__bf16)(acc[i][j][1] + bv),
                                 (__bf16)(acc[i][j][2] + bv), (__bf16)(acc[i][j][3] + bv)};
                    *(bf16x4*)&Vp[(size_t)(((b << 4) + h) * 64 + d) * 2048 + n] = vv;
                } else {
                    for (int rg = 0; rg < 4; ++rg) {
                        int rr = rbase + rg;
                        int b = rr >> 11, n = rr & 2047;
                        float v = acc[i][j][rg] + bv;
                        if (which == 0)
                            Qp[(size_t)(((b << 4) + h) * 2048 + n) * 64 + d] =
                                (__bf16)(v * QSCALE);
                        else
                            Kp[(size_t)(((b << 4) + h) * 2048 + n) * 64 + d] = (__bf16)v;
                    }
                }
            } else {
                for (int rg = 0; rg < 4; ++rg)
                    outp[(size_t)(rbase + rg) * Nn + c] = acc[i][j][rg] + bv;
            }
        }
    }
}

// ---------------------------------------------------------------------------
// Flash attention v5: grid (N/128, B*H); block 256 = 4 waves, 32 q-rows/wave.
// 32x32x16 MFMA throughout. S^T = K Q^T (A=K frags from LDS, B=Q from regs);
// P relayout C->A via lane^32 shuffle (NO P LDS buffer); PV with B=V^T frags.
// K/V LDS rows are 128B with 16B-unit XOR swizzle (unit ^= row&7), staged via
// global_load_lds with the matching permuted global source (coalescing kept).
// Rowsum via ones-MFMA (acc_l reg<->q map matches O). LDS 32KB, 4 blocks/CU.
__global__ __launch_bounds__(256, 4) void flash_attn5(const __bf16* __restrict__ Q,
                                                      const __bf16* __restrict__ K,
                                                      const __bf16* __restrict__ Vt,
                                                      __bf16* __restrict__ O) {
    __shared__ __align__(16) __bf16 Kts[2][4096];  // [buf][kpos 64][64 d] swizzled
    __shared__ __align__(16) __bf16 Vts[2][4096];  // [buf][d 64][64 kpos] swizzled
    const int tid = threadIdx.x, lane = tid & 63, w = tid >> 6;
    const int l31 = lane & 31, h = lane >> 5;
    const int bh = blockIdx.y;
    const int q0 = blockIdx.x * 128;
    const __bf16* Kb = K + (size_t)bh * 2048 * 64;
    const __bf16* Vb = Vt + (size_t)bh * 64 * 2048;

    // Q B-fragments (32x32x16): n=q=l31, k(d) = c*16 + h*8 + j  — from global
    const __bf16* Qg = Q + ((size_t)bh * 2048 + q0 + w * 32 + l31) * 64;
    bf16x8 qf[4];
#pragma unroll
    for (int c = 0; c < 4; ++c)
        qf[c] = *(const bf16x8*)(Qg + c * 16 + h * 8);

    bf16x8 ones;
#pragma unroll
    for (int i = 0; i < 8; ++i) ones[i] = (__bf16)1.0f;

    f32x16 acc[2];   // O[q 32][d 64]: [dtile]; C-layout rows=q
    acc[0] = (f32x16)0.f;
    acc[1] = (f32x16)0.f;
    f32x16 accl = (f32x16)0.f;  // rowsum, same reg<->q map

    // fragment read offsets: unit = (2c+h) ^ (l31&7), same key for K and V
    const int key = l31 & 7;
    int koff[4];
#pragma unroll
    for (int c = 0; c < 4; ++c) koff[c] = ((2 * c + h) ^ key) * 8;
    const int rbase = l31 * 64;

    auto stage = [&](int kt, int buf) {
#pragma unroll
        for (int it = 0; it < 2; ++it) {
            int ci = 2 * w + it;              // 8 chunks of 8 rows (1KB each)
            int rloc = ci * 8 + (lane >> 3);  // tile row 0..63
            int ulog = (lane & 7) ^ (lane >> 3);  // permuted global 16B unit
            gload_lds16(Kb + (size_t)(kt * 64 + rloc) * 64 + ulog * 8,
                        &Kts[buf][ci * 512]);
            gload_lds16(Vb + (size_t)rloc * 2048 + kt * 64 + ulog * 8,
                        &Vts[buf][ci * 512]);
        }
    };

    stage(0, 0);

    for (int kt = 0; kt < 32; ++kt) {
        const int cur = kt & 1;
        __syncthreads();  // publishes stage(kt); reads of buf[cur] from kt-2 done
        if (kt < 31) stage(kt + 1, cur ^ 1);  // drains at next barrier, overlapped

        const __bf16* Kc = Kts[cur];
        const __bf16* Vc = Vts[cur];

#pragma unroll
        for (int T = 0; T < 2; ++T) {  // kpos half-tile (32 kpos)
            // S^T[kpos 32][q 32] = K . Q^T over d=64 (4 chunks)
            f32x16 sacc = (f32x16)0.f;
#pragma unroll
            for (int c = 0; c < 4; ++c) {
                bf16x8 kf = *(const bf16x8*)&Kc[T * 2048 + rbase + koff[c]];
                sacc = MFMA32(kf, qf[c], sacc);
            }
            // exp2 + pack to bf16 pairs; reg pair (2r2,2r2+1) = consecutive kpos
            unsigned pk[8];
#pragma unroll
            for (int r2 = 0; r2 < 8; ++r2) {
                bf16x2 pp = {(__bf16)__builtin_exp2f(sacc[2 * r2]),
                             (__bf16)__builtin_exp2f(sacc[2 * r2 + 1])};
                pk[r2] = __builtin_bit_cast(unsigned, pp);
            }
            // build PV A-frags per 16-kpos chunk cc: 2 local regs + 2 via lane^32
#pragma unroll
            for (int cc = 0; cc < 2; ++cc) {
                unsigned tA = h ? pk[4 * cc] : pk[4 * cc + 2];
                unsigned tB = h ? pk[4 * cc + 1] : pk[4 * cc + 3];
                unsigned rA = (unsigned)__shfl_xor((int)tA, 32, 64);
                unsigned rB = (unsigned)__shfl_xor((int)tB, 32, 64);
                uint4v fu = {h ? rA : pk[4 * cc], h ? rB : pk[4 * cc + 1],
                             h ? pk[4 * cc + 2] : rA, h ? pk[4 * cc + 3] : rB};
                bf16x8 fragP = __builtin_bit_cast(bf16x8, fu);
                const int cg = T * 2 + cc;  // global kpos chunk 0..3
#pragma unroll
                for (int t = 0; t < 2; ++t) {
                    bf16x8 vf = *(const bf16x8*)&Vc[t * 2048 + rbase + koff[cg]];
                    acc[t] = MFMA32(fragP, vf, acc[t]);
                }
                accl = MFMA32(fragP, ones, accl);
            }
        }
    }

    // epilogue: C-layout row q = (reg&3)+8*(reg>>2)+4h, col d = t*32+l31
    const int b = bh >> 4, hd = bh & 15;
#pragma unroll
    for (int reg = 0; reg < 16; ++reg) {
        int qloc = (reg & 3) + 8 * (reg >> 2) + 4 * h;
        int qg = q0 + w * 32 + qloc;
        float linv = 1.0f / accl[reg];
        __bf16* orow = O + ((size_t)(b * 2048 + qg)) * 1024 + hd * 64;
        orow[l31] = (__bf16)(acc[0][reg] * linv);
        orow[32 + l31] = (__bf16)(acc[1][reg] * linv);
    }
}

// ---------------------------------------------------------------------------
extern "C" void kernel_launch(void* const* d_in, const int* in_sizes, int n_in,
                              void* d_out, int out_size, void* d_ws, size_t ws_size,
                              hipStream_t stream) {
    const float* x      = (const float*)d_in[0];  // [4,2048,1024]
    const float* qkv_w  = (const float*)d_in[1];  // [1024,3072]
    const float* qkv_b  = (const float*)d_in[2];  // [3072]
    const float* proj_w = (const float*)d_in[3];  // [1024,1024]
    const float* proj_b = (const float*)d_in[4];  // [1024]
    float* out = (float*)d_out;                   // [4,2048,1024]

    char* ws = (char*)d_ws;
    // layout (72 MB total); AttnOut aliases Xb (dead after GEMM1)
    __bf16* Xb     = (__bf16*)(ws);               // 16,777,216 B
    __bf16* Wqkvt  = (__bf16*)(ws + 16777216);    //  6,291,456 B
    __bf16* Wpt    = (__bf16*)(ws + 23068672);    //  2,097,152 B
    __bf16* Qb     = (__bf16*)(ws + 25165824);    // 16,777,216 B  (prescaled)
    __bf16* Kb     = (__bf16*)(ws + 41943040);    // 16,777,216 B
    __bf16* Vtb    = (__bf16*)(ws + 58720256);    // 16,777,216 B  ([b,h,d,n])
    __bf16* AttnOut = Xb;

    cvt_f32_bf16<<<8192, 256, 0, stream>>>(x, Xb, 2097152);
    transpose_cvt<<<dim3(96, 32), dim3(32, 8), 0, stream>>>(qkv_w, Wqkvt, 1024, 3072);
    transpose_cvt<<<dim3(32, 32), dim3(32, 8), 0, stream>>>(proj_w, Wpt, 1024, 1024);

    gemm_bt<0><<<dim3(24, 64), 256, 0, stream>>>(Xb, Wqkvt, qkv_b, nullptr,
                                                 Qb, Kb, Vtb, 8192, 3072, 1024);

    flash_attn5<<<dim3(16, 64), 256, 0, stream>>>(Qb, Kb, Vtb, AttnOut);

    gemm_bt<1><<<dim3(8, 64), 256, 0, stream>>>(AttnOut, Wpt, proj_b, out,
                                                nullptr, nullptr, nullptr, 8192, 1024, 1024);
}